// Round 6
// baseline (219.943 us; speedup 1.0000x reference)
//
#include <hip/hip_runtime.h>
#include <math.h>

#define NN 8192
#define DD 256
#define EPSV 1e-6f
#define BM 128
#define BN 64
#define CSPLIT 4
#define COLS_PER_BLOCK (NN / CSPLIT)  // 2048
#define NJT (COLS_PER_BLOCK / BN)     // 32
#define TSTR 266
// dynamic LDS: Kbuf[2] 64K | Ktbuf[2] 64K | P 16K (XOR-swizzled, stride 64)
#define SMEM_BYTES (65536 + 65536 + 16384)  // 147456

typedef __bf16 bf16x8 __attribute__((ext_vector_type(8)));
typedef float f32x16 __attribute__((ext_vector_type(16)));
typedef unsigned short ushort;
typedef unsigned int uint;

// ws layout (floats): Oacc[NN*DD] | lacc[NN] | qn[NN] | itv2[NN] | qbf[NN*DD/2] | qbfT[NN*DD/2]

__device__ inline ushort f2bf(float x) {
    uint u = __float_as_uint(x);
    u += 0x7fffu + ((u >> 16) & 1u);
    return (ushort)(u >> 16);
}

__device__ inline void gload_lds16(const void* g, void* l) {
    __builtin_amdgcn_global_load_lds((const __attribute__((address_space(1))) uint*)g,
                                     (__attribute__((address_space(3))) uint*)l, 16, 0, 0);
}

// Fused: zero Oacc/lacc slice + q -> qbf (swizzled), qbfT ([DD][NN]), qn, itv2
__global__ void prep_kernel(const float* __restrict__ q, const float* __restrict__ cp,
                            ushort* __restrict__ qbf, ushort* __restrict__ qbfT,
                            float* __restrict__ qn, float* __restrict__ itv2,
                            float* __restrict__ Oacc, float* __restrict__ lacc) {
    __shared__ ushort T[64 * TSTR];
    const int t = threadIdx.x;
    const int b = blockIdx.x;
    // zero Oacc slice: 16384 floats per block, coalesced
    float4 z4 = make_float4(0.f, 0.f, 0.f, 0.f);
    #pragma unroll
    for (int i = 0; i < 16; ++i) ((float4*)Oacc)[b * 4096 + i * 256 + t] = z4;
    if (t < 16) ((float4*)lacc)[b * 16 + t] = z4;

    const int p0 = b * 64;
    const int pr = t >> 2, fq = t & 3;
    const int row = p0 + pr;
    const float4* src = (const float4*)(q + (size_t)row * DD + fq * 64);
    ushort loc[64];
    float ss = 0.f;
    #pragma unroll
    for (int i = 0; i < 16; ++i) {
        float4 v = src[i];
        ushort b0 = f2bf(v.x), b1 = f2bf(v.y), b2 = f2bf(v.z), b3 = f2bf(v.w);
        loc[i * 4 + 0] = b0; loc[i * 4 + 1] = b1; loc[i * 4 + 2] = b2; loc[i * 4 + 3] = b3;
        float r0 = __uint_as_float((uint)b0 << 16), r1 = __uint_as_float((uint)b1 << 16);
        float r2 = __uint_as_float((uint)b2 << 16), r3 = __uint_as_float((uint)b3 << 16);
        ss += r0 * r0 + r1 * r1 + r2 * r2 + r3 * r3;
    }
    #pragma unroll
    for (int k = 0; k < 8; ++k)
        *(uint4*)(qbf + (size_t)row * DD + (((fq * 8 + k) ^ (row & 7)) * 8)) = *(uint4*)&loc[k * 8];
    #pragma unroll
    for (int k = 0; k < 32; ++k)
        *(ushort2*)&T[pr * TSTR + fq * 64 + k * 2] = *(ushort2*)&loc[k * 2];
    ss += __shfl_xor(ss, 1, 64);
    ss += __shfl_xor(ss, 2, 64);
    if (fq == 0) {
        float cc = fmaxf(cp[0], EPSV);
        qn[row] = ss;
        float tt = fmaxf(1.0f - cc * ss, EPSV);
        itv2[row] = sqrtf(2.0f * cc) / tt;
    }
    __syncthreads();
    #pragma unroll
    for (int pass = 0; pass < 4; ++pass) {
        int f = pass * 64 + (t >> 2);
        int quarter = t & 3;
        ushort tmp[16];
        #pragma unroll
        for (int i = 0; i < 16; ++i) tmp[i] = T[(quarter * 16 + i) * TSTR + f];
        *(uint4*)(qbfT + (size_t)f * NN + p0 + quarter * 16) = *(uint4*)&tmp[0];
        *(uint4*)(qbfT + (size_t)f * NN + p0 + quarter * 16 + 8) = *(uint4*)&tmp[8];
    }
}

__global__ __launch_bounds__(512, 2) void flash_kernel(
    const ushort* __restrict__ qbf, const ushort* __restrict__ qbfT,
    const float* __restrict__ cp, const float* __restrict__ qn,
    const float* __restrict__ itv2, float* __restrict__ Oacc, float* __restrict__ lacc) {
    extern __shared__ char smem[];
    ushort* Plds = (ushort*)(smem + 131072);  // [128 rows][64 j], XOR chunk swizzle

    const int tid = threadIdx.x;
    const int lane = tid & 63;
    const int w = tid >> 6;     // 0..7
    const int l31 = lane & 31;
    const int lhi = lane >> 5;
    // S mapping: 4 row-quads x 2 col-quads
    const int qr = w >> 1;
    const int qc = w & 1;
    // PV mapping: 2 row-pairs x 4 feature-quarters
    const int qr2 = w >> 2;     // 0..1 : rows qr2*64 .. +64
    const int fc = w & 3;       // 0..3 : feats fc*64 .. +64

    // XCD-locality remap: col-split pinned per XCD (lid%8 ~ XCD)
    const int lid = blockIdx.x;
    const int cs = lid & 3;
    const int rb = lid >> 2;
    const int R0 = rb * BM;
    const int C0 = cs * COLS_PER_BLOCK;

    const float cc = fmaxf(cp[0], EPSV);
    const float nrsc = -rsqrtf(cc);

    // persistent Q A-fragments (S rows qr*32 + l31, all 256 K)
    const int rowA = R0 + qr * 32 + l31;
    const ushort* qrow = qbf + (size_t)rowA * DD;
    bf16x8 qa[16];
    #pragma unroll
    for (int kk = 0; kk < 16; ++kk) {
        int c = kk * 2 + lhi;
        qa[kk] = *(const bf16x8*)(qrow + ((c ^ (rowA & 7)) * 8));
    }

    float qnr16[16], itr16[16];
    #pragma unroll
    for (int r = 0; r < 16; ++r) {
        int row = R0 + qr * 32 + (r & 3) + 8 * (r >> 2) + 4 * lhi;
        qnr16[r] = qn[row];
        itr16[r] = itv2[row];
    }

    f32x16 o[2][2];
    #pragma unroll
    for (int a = 0; a < 2; ++a)
        #pragma unroll
        for (int bb = 0; bb < 2; ++bb)
            #pragma unroll
            for (int i = 0; i < 16; ++i) o[a][bb][i] = 0.f;
    float racc[16];
    #pragma unroll
    for (int r = 0; r < 16; ++r) racc[r] = 0.f;

    // ---- stage K(0) + Kt(0) into buffer 0 ----
    {
        const char* g = (const char*)(qbf + (size_t)C0 * DD);
        #pragma unroll
        for (int i = 0; i < 4; ++i) {
            int base = i * 8192 + w * 1024;
            gload_lds16(g + base + lane * 16, smem + base);
        }
        #pragma unroll
        for (int i = 0; i < 4; ++i) {
            int f0 = i * 64 + w * 8;
            int f = f0 + (lane >> 3);
            const char* gk = (const char*)(qbfT + (size_t)f * NN + C0) +
                             (((lane & 7) ^ (f & 7)) * 16);
            gload_lds16(gk, smem + 65536 + f0 * 128);
        }
    }

    #pragma unroll 1
    for (int jt = 0; jt < NJT; ++jt) {
        const int C = C0 + jt * BN;
        const int cur = jt & 1;
        const ushort* Kc = (const ushort*)(smem + cur * 32768);
        const ushort* Ktc = (const ushort*)(smem + 65536 + cur * 32768);
        __syncthreads();  // A: K(jt)/Kt(jt) arrived (issued a full iter ago); Plds free

        // ---- issue K(jt+1) + Kt(jt+1) into the other buffers ----
        if (jt + 1 < NJT) {
            const int nxt = cur ^ 1;
            const char* g = (const char*)(qbf + (size_t)(C + BN) * DD);
            #pragma unroll
            for (int i = 0; i < 4; ++i) {
                int base = i * 8192 + w * 1024;
                gload_lds16(g + base + lane * 16, smem + nxt * 32768 + base);
            }
            #pragma unroll
            for (int i = 0; i < 4; ++i) {
                int f0 = i * 64 + w * 8;
                int f = f0 + (lane >> 3);
                const char* gk = (const char*)(qbfT + (size_t)f * NN + C + BN) +
                                 (((lane & 7) ^ (f & 7)) * 16);
                gload_lds16(gk, smem + 65536 + nxt * 32768 + f0 * 128);
            }
        }

        // per-jt column constants (issue early, used after S)
        const int jrow = qc * 32 + l31;
        const float qnj = qn[C + jrow];
        const float itj = itv2[C + jrow];

        // ---- S = Q . K^T (wave: rows 32*qr, cols 32*qc) ----
        f32x16 s;
        #pragma unroll
        for (int i = 0; i < 16; ++i) s[i] = 0.f;
        const ushort* krow = Kc + jrow * DD;
        #pragma unroll
        for (int kk = 0; kk < 16; ++kk) {
            int c = kk * 2 + lhi;
            bf16x8 b = *(const bf16x8*)(krow + ((c ^ (jrow & 7)) * 8));
            s = __builtin_amdgcn_mfma_f32_32x32x16_bf16(qa[kk], b, s, 0, 0, 0);
        }

        // ---- elementwise hyperbolic -> P (XOR-swizzled LDS) ----
        {
            const int jchunk = jrow >> 3;   // stored-chunk base for this lane's col
            const int jlow = jrow & 7;
            #pragma unroll
            for (int r = 0; r < 16; ++r) {
                float qsum = qnr16[r] + qnj;
                float itrj = itr16[r] * itj;
                float diff = fmaf(-2.0f, s[r], qsum);
                float z = fmaf(diff, itrj, 1.0f);
                z = fmaxf(z, 1.0f + EPSV) + EPSV;
                float y = z + sqrtf(fmaf(z, z, -1.0f));
                float p = __builtin_amdgcn_exp2f(nrsc * __builtin_amdgcn_logf(y));
                racc[r] += p;
                int mloc = qr * 32 + (r & 3) + 8 * (r >> 2) + 4 * lhi;
                int idx = mloc * 64 + ((jchunk ^ (mloc & 7)) * 8) + jlow;
                ((__bf16*)Plds)[idx] = (__bf16)p;
            }
        }
        __syncthreads();  // B: P visible; (K/Kt(jt+1) loads keep flying past? drained here — full S+elem cover)

        // ---- O += P . V (PV mapping: rows qr2*64, feats fc*64) ----
        #pragma unroll
        for (int kt = 0; kt < 4; ++kt) {
            bf16x8 pa[2], vb[2];
            #pragma unroll
            for (int cq = 0; cq < 2; ++cq) {
                int m = qr2 * 64 + cq * 32 + l31;
                int chunk = (kt * 2 + lhi) ^ (m & 7);
                pa[cq] = *(const bf16x8*)(Plds + m * 64 + chunk * 8);
            }
            #pragma unroll
            for (int cf = 0; cf < 2; ++cf) {
                int f = fc * 64 + cf * 32 + l31;
                int cj = kt * 2 + lhi;
                vb[cf] = *(const bf16x8*)(Ktc + f * 64 + ((cj ^ (f & 7)) * 8));
            }
            #pragma unroll
            for (int cq = 0; cq < 2; ++cq)
                #pragma unroll
                for (int cf = 0; cf < 2; ++cf)
                    o[cq][cf] = __builtin_amdgcn_mfma_f32_32x32x16_bf16(pa[cq], vb[cf], o[cq][cf], 0, 0, 0);
        }
    }

    // ---- epilogue (PV mapping) ----
    #pragma unroll
    for (int cq = 0; cq < 2; ++cq)
        #pragma unroll
        for (int cf = 0; cf < 2; ++cf)
            #pragma unroll
            for (int r = 0; r < 16; ++r) {
                int row = R0 + qr2 * 64 + cq * 32 + (r & 3) + 8 * (r >> 2) + 4 * lhi;
                int d = fc * 64 + cf * 32 + l31;
                atomicAdd(&Oacc[(size_t)row * DD + d], o[cq][cf][r]);
            }
    // softmax denom partials (S mapping)
    #pragma unroll
    for (int off = 1; off <= 16; off <<= 1)
        #pragma unroll
        for (int r = 0; r < 16; ++r) racc[r] += __shfl_xor(racc[r], off, 64);
    if (l31 == 0) {
        #pragma unroll
        for (int r = 0; r < 16; ++r) {
            int row = R0 + qr * 32 + (r & 3) + 8 * (r >> 2) + 4 * lhi;
            atomicAdd(&lacc[row], racc[r]);
        }
    }
}

__global__ void norm_kernel(const float* __restrict__ Oacc, const float* __restrict__ lacc,
                            float* __restrict__ out) {
    int i = blockIdx.x * 256 + threadIdx.x;
    float4 v = ((const float4*)Oacc)[i];
    float inv = 1.0f / lacc[i >> 6];
    ((float4*)out)[i] = make_float4(v.x * inv, v.y * inv, v.z * inv, v.w * inv);
}

extern "C" void kernel_launch(void* const* d_in, const int* in_sizes, int n_in,
                              void* d_out, int out_size, void* d_ws, size_t ws_size,
                              hipStream_t stream) {
    (void)in_sizes; (void)n_in; (void)out_size; (void)ws_size;
    const float* q = (const float*)d_in[0];
    const float* cp = (const float*)d_in[1];
    float* out = (float*)d_out;
    float* ws = (float*)d_ws;
    float* Oacc = ws;
    float* lacc = ws + (size_t)NN * DD;
    float* qn = lacc + NN;
    float* itv2 = qn + NN;
    ushort* qbf = (ushort*)(itv2 + NN);
    ushort* qbfT = qbf + (size_t)NN * DD;

    (void)hipFuncSetAttribute((const void*)flash_kernel,
                              hipFuncAttributeMaxDynamicSharedMemorySize, SMEM_BYTES);

    prep_kernel<<<NN / 64, 256, 0, stream>>>(q, cp, qbf, qbfT, qn, itv2, Oacc, lacc);
    flash_kernel<<<CSPLIT * (NN / BM), 512, SMEM_BYTES, stream>>>(qbf, qbfT, cp, qn, itv2, Oacc, lacc);
    norm_kernel<<<(NN * DD / 4) / 256, 256, 0, stream>>>(Oacc, lacc, out);
}